// Round 10
// baseline (183.193 us; speedup 1.0000x reference)
//
#include <hip/hip_runtime.h>

#define S_LEN 2048
#define NH 16
#define HD 64
#define DM 1024
#define BSZ 2

typedef __bf16 bf16;
typedef __bf16 bf16x8 __attribute__((ext_vector_type(8)));
typedef float f32x4 __attribute__((ext_vector_type(4)));
typedef const unsigned int __attribute__((address_space(1)))* gas_ptr;
typedef unsigned int __attribute__((address_space(3)))* las_ptr;

__device__ __forceinline__ void gl_lds16(const bf16* g, bf16* l) {
  __builtin_amdgcn_global_load_lds((gas_ptr)g, (las_ptr)l, 16, 0, 0);
}

#define CFENCE asm volatile("" ::: "memory")

// ------- prep: cast x to bf16 (blocks 0..4095) + 4 weight transposes -------
__global__ __launch_bounds__(256) void k_prep(
    const float* __restrict__ x, bf16* __restrict__ xb,
    const float* __restrict__ W0, const float* __restrict__ W1,
    const float* __restrict__ W2, const float* __restrict__ W3,
    bf16* __restrict__ dqkv, bf16* __restrict__ df) {
  __shared__ float t[64][65];
  const int id = blockIdx.x;
  if (id < 4096) {
    int i = id * 256 + threadIdx.x;
    float4 v = ((const float4*)x)[i];
    union { ushort4 u; bf16 b[4]; } o;
    o.b[0] = (bf16)v.x; o.b[1] = (bf16)v.y; o.b[2] = (bf16)v.z; o.b[3] = (bf16)v.w;
    ((ushort4*)xb)[i] = o.u;
    return;
  }
  const int id2 = id - 4096;
  const int z = id2 >> 8;
  const float* W = (z == 0) ? W0 : (z == 1) ? W1 : (z == 2) ? W2 : W3;
  bf16* D = (z < 3) ? (dqkv + (size_t)z * 1048576) : df;
  int k0 = ((id2 >> 4) & 15) * 64, n0 = (id2 & 15) * 64;
  int c = threadIdx.x & 63, rr = threadIdx.x >> 6;
#pragma unroll
  for (int it = 0; it < 16; ++it) {
    int r = it * 4 + rr;
    t[r][c] = W[(size_t)(k0 + r) * DM + n0 + c];
  }
  __syncthreads();
#pragma unroll
  for (int it = 0; it < 16; ++it) {
    int r = it * 4 + rr;
    D[(size_t)(n0 + r) * DM + k0 + c] = (bf16)t[c][r];
  }
}

// ---------------- bf16 GEMM, BMxBN tile, BK=64, 4 waves ----------------
// (identical to r8 submission — counted-vmcnt pipeline + XCD-chunked grid
//  + V transposed through LDS; measured improvement, keep frozen)
template <int MODE, int BM, int BN>
__global__ __launch_bounds__(256) void k_gemm(
    const bf16* __restrict__ A, const bf16* __restrict__ Bt,
    const float* __restrict__ b0, const float* __restrict__ b1,
    const float* __restrict__ b2, void* __restrict__ Cout,
    bf16* __restrict__ VtOut, int M, int N, int K) {
  constexpr int NST = BM / 32 + BN / 32;
  __shared__ __align__(16) bf16 SA[2][BM * 64];
  __shared__ __align__(16) bf16 SB[2][BN * 64];
  constexpr int MIc = BM / 32, NIc = BN / 32;
  const int tid = threadIdx.x;
  const int l = tid & 63, w = tid >> 6;
  const int lm = l & 15, lg = l >> 4;
  const int id = blockIdx.x;
  const int xcd = id & 7, r2 = id >> 3;
  int bx, by;
  if (MODE == 0) {            // 32 x 24 tiles -> rect 8bm x 12bn per XCD
    bx = (xcd & 3) * 8 + (r2 & 7);
    by = (xcd >> 2) * 12 + (r2 >> 3);
  } else {                    // 64 x 8 tiles -> rect 16bm x 4bn per XCD
    bx = (xcd & 3) * 16 + (r2 & 15);
    by = (xcd >> 2) * 4 + (r2 >> 4);
  }
  const int bm = bx * BM, bn = by * BN;
  const int wm = (w >> 1) * (BM / 2), wn = (w & 1) * (BN / 2);

  f32x4 acc[MIc][NIc] = {};
  const bf16* Ag = A + (size_t)bm * K;
  const bf16* Bg = Bt + (size_t)bn * K;

  auto stage = [&](int k0, int bufi) {
#pragma unroll
    for (int it = 0; it < BM / 32; ++it) {
      int cl = it * 256 + tid;
      int row = cl >> 3;
      int cs = ((cl & 7) ^ (row & 7)) << 3;
      gl_lds16(Ag + (size_t)row * K + k0 + cs, &SA[bufi][(it * 256 + w * 64) * 8]);
    }
#pragma unroll
    for (int it = 0; it < BN / 32; ++it) {
      int cl = it * 256 + tid;
      int row = cl >> 3;
      int cs = ((cl & 7) ^ (row & 7)) << 3;
      gl_lds16(Bg + (size_t)row * K + k0 + cs, &SB[bufi][(it * 256 + w * 64) * 8]);
    }
  };

  stage(0, 0);
  const int nk = K >> 6;
  int buf = 0;
  for (int t = 0; t < nk; ++t) {
    if (t + 1 < nk) {
      stage((t + 1) << 6, buf ^ 1);
      if constexpr (NST == 8) {
        asm volatile("s_waitcnt vmcnt(8)" ::: "memory");
      } else {
        asm volatile("s_waitcnt vmcnt(6)" ::: "memory");
      }
    } else {
      asm volatile("s_waitcnt vmcnt(0)" ::: "memory");
    }
    __builtin_amdgcn_s_barrier();
    CFENCE;
    const bf16* As = SA[buf];
    const bf16* Bs = SB[buf];
#pragma unroll
    for (int kk = 0; kk < 2; ++kk) {
      bf16x8 af[MIc], bfr[NIc];
#pragma unroll
      for (int mi = 0; mi < MIc; ++mi) {
        int row = wm + mi * 16 + lm;
        af[mi] = *(const bf16x8*)&As[row * 64 + ((((kk << 2) + lg) ^ (row & 7)) << 3)];
      }
#pragma unroll
      for (int ni = 0; ni < NIc; ++ni) {
        int row = wn + ni * 16 + lm;
        bfr[ni] = *(const bf16x8*)&Bs[row * 64 + ((((kk << 2) + lg) ^ (row & 7)) << 3)];
      }
#pragma unroll
      for (int mi = 0; mi < MIc; ++mi)
#pragma unroll
        for (int ni = 0; ni < NIc; ++ni)
          acc[mi][ni] = __builtin_amdgcn_mfma_f32_16x16x32_bf16(
              af[mi], bfr[ni], acc[mi][ni], 0, 0, 0);
    }
    CFENCE;
    __builtin_amdgcn_s_barrier();
    CFENCE;
    buf ^= 1;
  }

  if (MODE == 0 && bn >= 2048) {
    // ---- V epilogue: LDS [n][m] transpose with granule-XOR swizzle ----
    bf16* sc = (bf16*)SA;  // 16384 elements = 128 x 128
#pragma unroll
    for (int ni = 0; ni < NIc; ++ni) {
      int n_l = wn + ni * 16 + lm;
      float bv = b2[(bn + n_l) & 1023];
#pragma unroll
      for (int mi = 0; mi < MIc; ++mi) {
        int g = ((wm + mi * 16) >> 2) + lg;
        int gp = g ^ ((n_l & 7) << 2);
        union { ushort4 u; bf16 bb[4]; } pkv;
#pragma unroll
        for (int r = 0; r < 4; ++r) pkv.bb[r] = (bf16)(acc[mi][ni][r] + bv);
        *(ushort4*)&sc[n_l * 128 + gp * 4] = pkv.u;
      }
    }
    __syncthreads();
    const int bq = bm >> 11, s0 = bm & 2047;
#pragma unroll
    for (int it2 = 0; it2 < 8; ++it2) {
      int row = it2 * 16 + (tid >> 4), c = tid & 15;
      int g0p = (2 * c) ^ ((row & 7) << 2);
      float4 val = *(const float4*)&sc[row * 128 + g0p * 4];
      int ng = bn + row;
      int hV = (ng >> 6) & 15;
      int d = ng & 63;
      *(float4*)&VtOut[((size_t)(bq * NH + hV) * HD + d) * S_LEN + s0 + c * 8] = val;
    }
    return;
  }

#pragma unroll
  for (int ni = 0; ni < NIc; ++ni) {
    int n = bn + wn + ni * 16 + lm;
    float bv;
    if (MODE == 0) {
      bv = (n < 1024) ? b0[n] : b1[n & 1023];
    } else {
      bv = b0[n];
    }
#pragma unroll
    for (int mi = 0; mi < MIc; ++mi) {
#pragma unroll
      for (int r = 0; r < 4; ++r) {
        int m = bm + wm + mi * 16 + lg * 4 + r;
        float v = acc[mi][ni][r] + bv;
        if (MODE == 0) {
          int qkv = n >> 10;
          int h = (n >> 6) & 15;
          int d = n & 63;
          int b = m >> 11, s = m & 2047;
          ((bf16*)Cout)[(size_t)qkv * (BSZ * NH * S_LEN * HD) +
                        ((size_t)(b * NH + h) * S_LEN + s) * HD + d] = (bf16)v;
        } else {
          ((float*)Cout)[(size_t)m * N + n] = v;
        }
      }
    }
  }
}

// ---------------- flash attention, bidirectional ALiBi ----------------
// Grid 512, one 128-row strip per block, 2 blocks/CU ALWAYS resident
// (16 waves/CU): independent co-resident blocks hide each other's barrier
// drains.  Loop reverted to the measured-faster single-__syncthreads form
// (r7 bench: 44.6us vs counted-vmcnt 53.3us) — stage(t+1) overlaps
// compute(t); the vmcnt(0) drain sits after compute, mostly hidden.
// Balance: within an XCD, CU k gets blocks lam=k and lam=k+32 (sequential
// fill); rank rho = lam<32 ? lam>>2 : 15-((lam-32)>>2) makes the two
// co-resident strips' tile counts sum to exactly 34 for both directions.
#define SMX(MASKED)                                                           \
  {                                                                           \
    const float t0 = slp2 * (float)dlo;                                       \
    _Pragma("unroll") for (int ni = 0; ni < 4; ++ni) {                        \
      const int koff = (ni & 1) * 32 + (ni >> 1) * 4;                         \
      float bni = t0 + dni[ni];                                               \
      float pr[4];                                                            \
      _Pragma("unroll") for (int r = 0; r < 4; ++r) {                         \
        float v = fmaf(sc[ni][r], c1, bni + srr[r]);                          \
        if (MASKED) {                                                         \
          int reli = dlo + koff + relc + r;                                   \
          bool ok = causal ? (reli <= 0) : (reli >= 0);                       \
          v = ok ? v : -1e9f;                                                 \
        }                                                                     \
        pr[r] = __builtin_amdgcn_exp2f(v);                                    \
      }                                                                       \
      union { bf16 b[2]; unsigned u; } u0, u1;                                \
      u0.b[0] = (bf16)pr[0]; u0.b[1] = (bf16)pr[1];                           \
      u1.b[0] = (bf16)pr[2]; u1.b[1] = (bf16)pr[3];                           \
      pk[ni][0] = u0.u; pk[ni][1] = u1.u;                                     \
    }                                                                         \
  }

__global__ __launch_bounds__(512, 2) void k_attn(const bf16* __restrict__ Qh,
                                                 const bf16* __restrict__ Kh,
                                                 const bf16* __restrict__ Vt,
                                                 bf16* __restrict__ O) {
  __shared__ __align__(16) bf16 Ks[2][4096];
  __shared__ __align__(16) bf16 Vs[2][4096];
  const int id = blockIdx.x;
  const int lam = id >> 3;
  const int bh = ((id & 7) << 2) | (lam & 3);
  const int rho = (lam < 32) ? (lam >> 2) : 15 - ((lam - 32) >> 2);
  const int b = bh >> 4, h = bh & 15;
  const bool causal = (h < 8);
  const int yi = causal ? (15 - rho) : rho;
  const int tid = threadIdx.x;
  const int w = tid >> 6, l = tid & 63;
  const int lm = l & 15, lg = l >> 4;
  const int hh = causal ? h : h - 8;
  const float c1 = 0.18033688f;  // 0.125 * log2(e)
  const float sm = __builtin_amdgcn_exp2f(-(float)(hh + 1) * 0.57312035f) * 1.44269504f;
  const float slp2 = causal ? sm : -sm;
  const int relc = lg * 8 - lm;
  const int krow_lane = ((lm >> 2) << 3) + (lm & 3);
  const int swzK = (lm & 3) | (((lm >> 2) & 1) << 2);
  const int swzV = (lm & 3) | (((lm >> 3) & 1) << 2);
  float dni[4], srr[4];
#pragma unroll
  for (int ni = 0; ni < 4; ++ni)
    dni[ni] = slp2 * (float)((ni & 1) * 32 + (ni >> 1) * 4);
#pragma unroll
  for (int r = 0; r < 4; ++r) srr[r] = slp2 * (float)(relc + r);

  const bf16* Qp = Qh + (size_t)bh * S_LEN * HD;
  const bf16* Kp = Kh + (size_t)bh * S_LEN * HD;
  const bf16* Vp = Vt + (size_t)bh * HD * S_LEN;

  bf16x8 ones;
#pragma unroll
  for (int i = 0; i < 8; ++i) ones[i] = (bf16)1.0f;

  auto stage = [&](bf16* lk, bf16* lv, int j0) {
    const int row = tid >> 3, c = tid & 7;
    const int sw = (row & 3) | (((row >> 3) & 1) << 2);
    const int gc = (c ^ sw) << 3;
    const int clb8 = ((tid >> 6) << 6) * 8;
    gl_lds16(Kp + (size_t)(j0 + row) * HD + gc, lk + clb8);
    gl_lds16(Vp + (size_t)row * S_LEN + j0 + gc, lv + clb8);
  };

  const int qb = yi << 7;
  const int q0 = qb + w * 16;
  const int jbase = causal ? 0 : qb;
  const int jcnt = causal ? (qb >> 6) + 2 : ((S_LEN - qb) >> 6);

  bf16x8 qf[2];
#pragma unroll
  for (int kk = 0; kk < 2; ++kk)
    qf[kk] = *(const bf16x8*)&Qp[(size_t)(q0 + lm) * HD + kk * 32 + lg * 8];

  f32x4 oacc[4] = {};
  f32x4 lacc = {};

  auto compute = [&](int t, const bf16* lk, const bf16* lv) {
    const int j0 = jbase + t * 64;
    const int dlo = j0 - q0;
    const bool skip = causal ? (dlo >= 16) : (dlo <= -64);
    if (skip) return;
    f32x4 sc[4] = {};
#pragma unroll
    for (int kk = 0; kk < 2; ++kk)
#pragma unroll
      for (int ni = 0; ni < 4; ++ni) {
        const int koff = (ni & 1) * 32 + (ni >> 1) * 4;
        bf16x8 kf = *(const bf16x8*)&lk[(koff + krow_lane) * 64 +
                                        ((((kk << 2) + lg) ^ swzK) << 3)];
        sc[ni] = __builtin_amdgcn_mfma_f32_16x16x32_bf16(kf, qf[kk], sc[ni],
                                                         0, 0, 0);
      }
    bf16x8 vf[2][4];
#pragma unroll
    for (int kk = 0; kk < 2; ++kk)
#pragma unroll
      for (int di = 0; di < 4; ++di)
        vf[kk][di] = *(const bf16x8*)&lv[(di * 16 + lm) * 64 +
                                         ((((kk << 2) + lg) ^ swzV) << 3)];
    const bool full = causal ? (dlo <= -63) : (dlo >= 15);
    unsigned pk[4][2];
    if (full) { SMX(false); } else { SMX(true); }
#pragma unroll
    for (int kk = 0; kk < 2; ++kk) {
      union { unsigned d[4]; bf16x8 v; } pa;
      pa.d[0] = pk[kk][0];
      pa.d[1] = pk[kk][1];
      pa.d[2] = pk[kk + 2][0];
      pa.d[3] = pk[kk + 2][1];
      lacc = __builtin_amdgcn_mfma_f32_16x16x32_bf16(pa.v, ones, lacc, 0, 0, 0);
#pragma unroll
      for (int di = 0; di < 4; ++di)
        oacc[di] = __builtin_amdgcn_mfma_f32_16x16x32_bf16(pa.v, vf[kk][di],
                                                           oacc[di], 0, 0, 0);
    }
  };

  stage(Ks[0], Vs[0], jbase);
  __syncthreads();
  for (int t = 0; t < jcnt; ++t) {
    const int cur = t & 1;
    if (t + 1 < jcnt) stage(Ks[cur ^ 1], Vs[cur ^ 1], jbase + (t + 1) * 64);
    compute(t, Ks[cur], Vs[cur]);
    __syncthreads();
  }

  float rin[4];
#pragma unroll
  for (int r = 0; r < 4; ++r) rin[r] = 1.0f / lacc[r];
#pragma unroll
  for (int di = 0; di < 4; ++di) {
    int d = h * HD + di * 16 + lm;
#pragma unroll
    for (int r = 0; r < 4; ++r) {
      int q = q0 + lg * 4 + r;
      O[((size_t)b * S_LEN + q) * DM + d] = (bf16)(oacc[di][r] * rin[r]);
    }
  }
}

extern "C" void kernel_launch(void* const* d_in, const int* in_sizes, int n_in,
                              void* d_out, int out_size, void* d_ws, size_t ws_size,
                              hipStream_t stream) {
  const float* x  = (const float*)d_in[0];
  const float* Wq = (const float*)d_in[1];
  const float* bq = (const float*)d_in[2];
  const float* Wk = (const float*)d_in[3];
  const float* bk = (const float*)d_in[4];
  const float* Wv = (const float*)d_in[5];
  const float* bv = (const float*)d_in[6];
  const float* Wf = (const float*)d_in[7];
  const float* bfp = (const float*)d_in[8];

  char* ws = (char*)d_ws;
  const size_t MB = 1ull << 20;
  bf16* xb    = (bf16*)(ws);            // 8 MB  x cast to bf16 [4096][1024]
  bf16* Wqkvt = (bf16*)(ws + 8 * MB);   // 6 MB  [3072][1024] (Wq|Wk|Wv)^T
  bf16* Wft   = (bf16*)(ws + 14 * MB);  // 2 MB  Wf^T
  bf16* QKVh  = (bf16*)(ws + 16 * MB);  // Q,K head layout [2][B][H][S][64]
  bf16* Vt    = (bf16*)(ws + 40 * MB);  // 8 MB  [B][H][64][S] (written by GEMM)
  bf16* O     = QKVh + 2 * 4194304;     // attention output [B][S][DM]

  k_prep<<<5120, 256, 0, stream>>>(x, xb, Wq, Wk, Wv, Wf, Wqkvt, Wft);
  k_gemm<0, 128, 128><<<768, 256, 0, stream>>>(
      xb, Wqkvt, bq, bk, bv, QKVh, Vt, 4096, 3072, 1024);
  k_attn<<<512, 512, 0, stream>>>(QKVh, QKVh + 4194304, Vt, O);
  k_gemm<2, 64, 128><<<512, 256, 0, stream>>>(
      O, Wft, bfp, bfp, bfp, d_out, nullptr, 4096, 1024, 1024);
}